// Round 13
// baseline (235.009 us; speedup 1.0000x reference)
//
#include <hip/hip_runtime.h>

// ---------- types ----------
typedef __bf16 bf16x8 __attribute__((ext_vector_type(8)));
typedef float  f32x4  __attribute__((ext_vector_type(4)));
typedef unsigned short us8 __attribute__((ext_vector_type(8)));

__device__ __forceinline__ unsigned short f2bf(float f) {
  unsigned int u = __builtin_bit_cast(unsigned int, f);
  u += 0x7FFFu + ((u >> 16) & 1u);   // round-to-nearest-even
  return (unsigned short)(u >> 16);
}
__device__ __forceinline__ float sigmoid_f(float x) {
  return 1.f / (1.f + __expf(-x));
}
// NaN-safe fast tanh: 1 - 2/(e^{2x}+1)
__device__ __forceinline__ float tanh_f(float x) {
  float e = __expf(2.f * x);
  return 1.f - 2.f / (e + 1.f);
}

// ---------- cast+relayout primitive: one wave converts a 16row x 32col f32
// region to slot-major bf16 (region image: elem = s4*128 + r16*8 + e).
// Coalesced global reads, transpose via +1-padded LDS, contiguous 16B writes.
__device__ __forceinline__ void relayout_region(
    const float* __restrict__ srcRowBase, size_t rowStride,
    unsigned short* __restrict__ dst, float* __restrict__ lp, int lane) {
  {
    int r = lane >> 2, c = (lane & 3) << 3;
    const float* s = srcRowBase + (size_t)r * rowStride + c;
    f32x4 a = *(const f32x4*)(s);
    f32x4 b = *(const f32x4*)(s + 4);
#pragma unroll
    for (int j = 0; j < 4; ++j) { lp[r * 33 + c + j] = a[j]; lp[r * 33 + c + 4 + j] = b[j]; }
  }
  int s4 = lane >> 4, r16 = lane & 15;
  us8 o;
#pragma unroll
  for (int j = 0; j < 8; ++j) o[j] = f2bf(lp[r16 * 33 + s4 * 8 + j]);
  *(us8*)(dst + lane * 8) = o;
}

// ---------- ONE merged prep kernel: all relayouts in a single launch ----------
__global__ __launch_bounds__(256) void prep_all(
    const float* __restrict__ inp, const float* __restrict__ hidden,
    const float* __restrict__ w_ih, const float* __restrict__ w_hh,
    const float* __restrict__ w_out,
    unsigned short* __restrict__ inp_r, unsigned short* __restrict__ h_r,
    unsigned short* __restrict__ wih_r, unsigned short* __restrict__ whh_r,
    unsigned short* __restrict__ wout_r)
{
  __shared__ float lp[4][16 * 33];
  const int wIn = threadIdx.x >> 6, lane = threadIdx.x & 63;
  const int gw  = blockIdx.x * 4 + wIn;

  const float* src; unsigned short* dst; int K, local, isA;
  if      (gw < 2048) { src = inp;    dst = inp_r;  K = 512;  isA = 1; local = gw; }
  else if (gw < 6144) { src = hidden; dst = h_r;    K = 1024; isA = 1; local = gw - 2048; }
  else if (gw < 6912) { src = w_ih;   dst = wih_r;  K = 512;  isA = 0; local = gw - 6144; }
  else if (gw < 8448) { src = w_hh;   dst = whh_r;  K = 1024; isA = 0; local = gw - 6912; }
  else                { src = w_out;  dst = wout_r; K = 1024; isA = 1; local = gw - 8448; }
  const int nkt = K >> 5;

  if (isA) {
    int p = local / nkt, kt = local - p * nkt;
    const float* base = src + (size_t)p * 128 * K + kt * 32;
    unsigned short* d = dst + (size_t)local * 4096;
#pragma unroll
    for (int g = 0; g < 8; ++g)
      relayout_region(base + (size_t)g * 16 * K, K, d + g * 512, lp[wIn], lane);
  } else {
    int qg = local / nkt, kt = local - qg * nkt;
    int q = qg / 3, g = qg - q * 3;
    const float* base = src + ((size_t)g * 1024 + q * 64) * K + kt * 32;
    unsigned short* d = dst + (size_t)local * 2048;
#pragma unroll
    for (int rg = 0; rg < 4; ++rg)
      relayout_region(base + (size_t)rg * 16 * K, K, d + rg * 512, lp[wIn], lane);
  }
}

#define GLOAD(gp, lp) __builtin_amdgcn_global_load_lds( \
    (const __attribute__((address_space(1))) unsigned int*)(gp), \
    (__attribute__((address_space(3))) unsigned int*)(lp), 16, 0, 0)

// ---------- Fused GRU cell: r12 structure + XCD-aware block swizzle.
// Swizzle groups blocks by W-panel column (x-major): XCD k owns x in
// {2k,2k+1} for the whole dispatch -> 1.2 MB W working set stays in that
// XCD's L2, removing ~7.6 TB/s of W re-read traffic from L3. ----------
__global__ __launch_bounds__(256, 2) void fused_gru(
    const unsigned short* __restrict__ inp_r,
    const unsigned short* __restrict__ h_r,
    const unsigned short* __restrict__ wih_r,
    const unsigned short* __restrict__ whh_r,
    const float* __restrict__ b_ih,
    const float* __restrict__ b_hh,
    const float* __restrict__ hidden,      // [B,1024] f32
    float* __restrict__ hnew_f32,
    unsigned short* __restrict__ hnew_img)
{
  __shared__ unsigned short ls[4][10240];   // 4 x 20KB rotation

  const int tid  = threadIdx.x;
  const int lane = tid & 63;
  const int wave = tid >> 6;
  const int wr = wave >> 1, wc = wave & 1;

  // XCD swizzle: hw launch-order id f (x fastest); logical L x-major.
  // 2048 blocks = 8 XCDs x 256; XCD(f) = f%8 -> owns logical x = {2k,2k+1}.
  const int f  = blockIdx.y * 16 + blockIdx.x;
  const int L  = (f & 7) * 256 + (f >> 3);
  const int bx = L >> 7;     // 0..15  W-panel column
  const int by = L & 127;    // 0..127 A row-panel

  f32x4 accR[4][2], accZ[4][2], accNi[4][2], accNh[4][2];
#pragma unroll
  for (int m = 0; m < 4; ++m)
#pragma unroll
    for (int n = 0; n < 2; ++n) {
      accR[m][n]  = f32x4{0.f, 0.f, 0.f, 0.f};
      accZ[m][n]  = f32x4{0.f, 0.f, 0.f, 0.f};
      accNi[m][n] = f32x4{0.f, 0.f, 0.f, 0.f};
      accNh[m][n] = f32x4{0.f, 0.f, 0.f, 0.f};
    }

  const int t4   = lane >> 4;                // k-octet 0..3
  const int l15  = lane & 15;
  const int rofs = t4 * 128 + l15 * 8;       // within-region read offset (elems)

  // induction staging pointers (wave-uniform; advance per step)
  const unsigned short* aptr = inp_r + (size_t)by * (16 * 4096);
  const unsigned short* wptr = wih_r + (size_t)bx * (3 * 16 * 2048);
  int wgs = 16 * 2048;                       // gate stride (elems)

#define STAGE(BUF) do { \
    GLOAD(aptr + tid * 8,           &ls[BUF][tid * 8]); \
    GLOAD(aptr + 2048 + tid * 8,    &ls[BUF][2048 + tid * 8]); \
    GLOAD(wptr + tid * 8,           &ls[BUF][4096 + tid * 8]); \
    GLOAD(wptr + wgs + tid * 8,     &ls[BUF][6144 + tid * 8]); \
    GLOAD(wptr + 2 * wgs + tid * 8, &ls[BUF][8192 + tid * 8]); \
    aptr += 4096; wptr += 2048; \
  } while (0)

#define COMPUTE(BUF, ACCN) do { \
    const unsigned short* lb = &ls[BUF][0]; \
    bf16x8 af[4], bfr[3][2]; \
    _Pragma("unroll") for (int m = 0; m < 4; ++m) \
      af[m] = *(const bf16x8*)&lb[(wr * 4 + m) * 512 + rofs]; \
    _Pragma("unroll") for (int g = 0; g < 3; ++g) { \
      _Pragma("unroll") for (int n = 0; n < 2; ++n) \
        bfr[g][n] = *(const bf16x8*)&lb[4096 + g * 2048 + (wc * 2 + n) * 512 + rofs]; \
    } \
    __builtin_amdgcn_s_setprio(1); \
    _Pragma("unroll") for (int m = 0; m < 4; ++m) { \
      _Pragma("unroll") for (int n = 0; n < 2; ++n) { \
        accR[m][n] = __builtin_amdgcn_mfma_f32_16x16x32_bf16(af[m], bfr[0][n], accR[m][n], 0, 0, 0); \
        accZ[m][n] = __builtin_amdgcn_mfma_f32_16x16x32_bf16(af[m], bfr[1][n], accZ[m][n], 0, 0, 0); \
        ACCN[m][n] = __builtin_amdgcn_mfma_f32_16x16x32_bf16(af[m], bfr[2][n], ACCN[m][n], 0, 0, 0); \
      } \
    } \
    __builtin_amdgcn_s_setprio(0); \
  } while (0)

#define WAIT10 asm volatile("s_waitcnt vmcnt(10)" ::: "memory")
#define BARR   __builtin_amdgcn_s_barrier()
#define STEP(SB, CB, ACCN) do { STAGE(SB); WAIT10; BARR; COMPUTE(CB, ACCN); } while (0)

  // 48 kt32 tiles: 0..15 inp/wih -> accNi, 16..47 h/whh -> accNh
  STAGE(0); STAGE(1);                        // tiles 0,1
#pragma unroll 1
  for (int i = 0; i < 3; ++i) {              // t = 0..11, stage 2..13
    STEP(2, 0, accNi); STEP(3, 1, accNi); STEP(0, 2, accNi); STEP(1, 3, accNi);
  }
  STEP(2, 0, accNi);                         // t=12, stage 14
  STEP(3, 1, accNi);                         // t=13, stage 15
  aptr = h_r + (size_t)by * (32 * 4096);     // switch to h-phase
  wptr = whh_r + (size_t)bx * (3 * 32 * 2048);
  wgs = 32 * 2048;
  STEP(0, 2, accNi);                         // t=14, stage 16
  STEP(1, 3, accNi);                         // t=15, stage 17
#pragma unroll 1
  for (int i = 0; i < 7; ++i) {              // t = 16..43, stage 18..45
    STEP(2, 0, accNh); STEP(3, 1, accNh); STEP(0, 2, accNh); STEP(1, 3, accNh);
  }
  STEP(2, 0, accNh);                         // t=44, stage 46
  STEP(3, 1, accNh);                         // t=45, stage 47
  asm volatile("s_waitcnt vmcnt(5)" ::: "memory"); BARR;
  COMPUTE(2, accNh);                         // t=46
  asm volatile("s_waitcnt vmcnt(0)" ::: "memory"); BARR;
  COMPUTE(3, accNh);                         // t=47

#undef STAGE
#undef COMPUTE
#undef WAIT10
#undef BARR
#undef STEP

  // ---- epilogue: gate math + blend ----
  // C/D layout: col = lane&15, row = (lane>>4)*4 + r
  const int m0 = by * 128;
  const int n0 = bx * 64;
  const int colb = n0 + wc * 32 + l15;
  const int rowb = m0 + wr * 64 + (t4 << 2);
#pragma unroll
  for (int n = 0; n < 2; ++n) {
    int c = colb + n * 16;
    float br  = b_ih[c]        + b_hh[c];
    float bz  = b_ih[1024 + c] + b_hh[1024 + c];
    float bni = b_ih[2048 + c];
    float bnh = b_hh[2048 + c];
    const int kt = c >> 5;                 // image k-chunk
    const int s  = (c >> 3) & 3;           // k-octet slot
    const int e  = c & 7;
#pragma unroll
    for (int m = 0; m < 4; ++m) {
      int row = rowb + m * 16;
#pragma unroll
      for (int r = 0; r < 4; ++r) {
        float rg = sigmoid_f(accR[m][n][r] + br);
        float zg = sigmoid_f(accZ[m][n][r] + bz);
        float ng = tanh_f((accNi[m][n][r] + bni) + rg * (accNh[m][n][r] + bnh));
        int rw = row + r;
        float ho = hidden[(size_t)rw * 1024 + c];
        float hv = (1.f - zg) * ng + zg * ho;
        hnew_f32[(size_t)rw * 1024 + c] = hv;
        // slot-major GEMM A-image: tile (p*32+kt), region (row>>4)&7
        size_t img = ((size_t)((rw >> 7) * 32 + kt)) * 4096
                   + (((rw >> 4) & 7) * 512) + s * 128 + (rw & 15) * 8 + e;
        hnew_img[img] = f2bf(hv);
      }
    }
  }
}

// ---------- out GEMM: r12 structure + XCD swizzle (512 = 8 x 64). ----------
__global__ __launch_bounds__(256, 2) void gemm_out(
    const unsigned short* __restrict__ A_img,   // [128 p-tiles][32 kt][4096]
    const unsigned short* __restrict__ B_img,   // [4 p-tiles][32 kt][4096]
    float* __restrict__ Cout,
    const float* __restrict__ bias)
{
  __shared__ unsigned short ls[4][8192];   // 4 x 16KB rotation (A 4096 | B 4096)

  const int tid  = threadIdx.x;
  const int lane = tid & 63;
  const int wave = tid >> 6;
  const int wr = wave >> 1, wc = wave & 1;

  const int f  = blockIdx.y * 4 + blockIdx.x;
  const int L  = (f & 7) * 64 + (f >> 3);
  const int bx = L >> 7;     // 0..3
  const int by = L & 127;    // 0..127

  f32x4 acc[4][4];
#pragma unroll
  for (int i = 0; i < 4; ++i)
#pragma unroll
    for (int j = 0; j < 4; ++j) acc[i][j] = f32x4{0.f, 0.f, 0.f, 0.f};

  const int t4   = lane >> 4;
  const int l15  = lane & 15;
  const int rofs = t4 * 128 + l15 * 8;

  const unsigned short* aptr = A_img + (size_t)by * (32 * 4096);
  const unsigned short* bptr = B_img + (size_t)bx * (32 * 4096);

#define STAGE(BUF) do { \
    GLOAD(aptr + tid * 8,        &ls[BUF][tid * 8]); \
    GLOAD(aptr + 2048 + tid * 8, &ls[BUF][2048 + tid * 8]); \
    GLOAD(bptr + tid * 8,        &ls[BUF][4096 + tid * 8]); \
    GLOAD(bptr + 2048 + tid * 8, &ls[BUF][6144 + tid * 8]); \
    aptr += 4096; bptr += 4096; \
  } while (0)

#define COMPUTE(BUF) do { \
    const unsigned short* lb = &ls[BUF][0]; \
    bf16x8 af[4], bfr[4]; \
    _Pragma("unroll") for (int m = 0; m < 4; ++m) \
      af[m] = *(const bf16x8*)&lb[(wr * 4 + m) * 512 + rofs]; \
    _Pragma("unroll") for (int n = 0; n < 4; ++n) \
      bfr[n] = *(const bf16x8*)&lb[4096 + (wc * 4 + n) * 512 + rofs]; \
    __builtin_amdgcn_s_setprio(1); \
    _Pragma("unroll") for (int m = 0; m < 4; ++m) { \
      _Pragma("unroll") for (int n = 0; n < 4; ++n) \
        acc[m][n] = __builtin_amdgcn_mfma_f32_16x16x32_bf16(af[m], bfr[n], acc[m][n], 0, 0, 0); \
    } \
    __builtin_amdgcn_s_setprio(0); \
  } while (0)

#define WAIT8 asm volatile("s_waitcnt vmcnt(8)" ::: "memory")
#define BARR  __builtin_amdgcn_s_barrier()
#define STEP(SB, CB) do { STAGE(SB); WAIT8; BARR; COMPUTE(CB); } while (0)

  STAGE(0); STAGE(1);
#pragma unroll 1
  for (int i = 0; i < 7; ++i) {              // t = 0..27, stage 2..29
    STEP(2, 0); STEP(3, 1); STEP(0, 2); STEP(1, 3);
  }
  STEP(2, 0);                                // t=28, stage 30
  STEP(3, 1);                                // t=29, stage 31
  asm volatile("s_waitcnt vmcnt(4)" ::: "memory"); BARR;
  COMPUTE(2);                                // t=30
  asm volatile("s_waitcnt vmcnt(0)" ::: "memory"); BARR;
  COMPUTE(3);                                // t=31

#undef STAGE
#undef COMPUTE
#undef WAIT8
#undef BARR
#undef STEP

  const int m0 = by * 128;
  const int n0 = bx * 128;
  const int colb = n0 + wc * 64 + l15;
  const int rowb = m0 + wr * 64 + (t4 << 2);
#pragma unroll
  for (int n = 0; n < 4; ++n) {
    int col = colb + n * 16;
    float bv = bias[col];
#pragma unroll
    for (int m = 0; m < 4; ++m) {
      int row = rowb + m * 16;
#pragma unroll
      for (int r = 0; r < 4; ++r) {
        Cout[(size_t)(row + r) * 512 + col] = tanh_f(acc[m][n][r] + bv);
      }
    }
  }
}

// ---------- launch ----------
extern "C" void kernel_launch(void* const* d_in, const int* in_sizes, int n_in,
                              void* d_out, int out_size, void* d_ws, size_t ws_size,
                              hipStream_t stream) {
  const int B = 16384, H = 1024, O = 512;
  const float* inp    = (const float*)d_in[0];
  const float* hidden = (const float*)d_in[1];
  const float* w_ih   = (const float*)d_in[2];
  const float* w_hh   = (const float*)d_in[3];
  const float* b_ih   = (const float*)d_in[4];
  const float* b_hh   = (const float*)d_in[5];
  const float* w_out  = (const float*)d_in[6];
  const float* b_out  = (const float*)d_in[7];

  float* out      = (float*)d_out;                     // [B, O] f32
  float* hnew_out = out + (size_t)B * O;               // [1, B, H] f32

  char* ws = (char*)d_ws;
  size_t need = 0;
  auto carve = [&](size_t elems) {
    unsigned short* p = (unsigned short*)(ws + need);
    need += elems * 2;
    return p;
  };
  unsigned short* inp_r  = carve((size_t)B * O);       // 16 MB (image)
  unsigned short* h_r    = carve((size_t)B * H);       // 32 MB (image)
  unsigned short* wih_r  = carve((size_t)3 * H * O);   // 3 MB (image)
  unsigned short* whh_r  = carve((size_t)3 * H * H);   // 6 MB (image)
  unsigned short* wout_r = carve((size_t)O * H);       // 1 MB (image)
  unsigned short* hnew_i = carve((size_t)B * H);       // 32 MB (image)
  if (ws_size < need) return;

  // one merged prep launch: 8576 waves -> 2144 blocks
  prep_all<<<dim3(2144), dim3(256), 0, stream>>>(
      inp, hidden, w_ih, w_hh, w_out, inp_r, h_r, wih_r, whh_r, wout_r);

  // fused GRU cell -> h_new (f32 into d_out tail, bf16 image into ws)
  fused_gru<<<dim3(H / 64, B / 128), dim3(256), 0, stream>>>(
      inp_r, h_r, wih_r, whh_r, b_ih, b_hh, hidden, hnew_out, hnew_i);

  // out = tanh(h_new @ w_out^T + b_out)
  gemm_out<<<dim3(O / 128, B / 128), dim3(256), 0, stream>>>(
      hnew_i, wout_r, out, b_out);
}

// Round 14
// 219.405 us; speedup vs baseline: 1.0711x; 1.0711x over previous
//
#include <hip/hip_runtime.h>

// ---------- types ----------
typedef __bf16 bf16x8 __attribute__((ext_vector_type(8)));
typedef float  f32x4  __attribute__((ext_vector_type(4)));
typedef unsigned short us8 __attribute__((ext_vector_type(8)));

__device__ __forceinline__ unsigned short f2bf(float f) {
  unsigned int u = __builtin_bit_cast(unsigned int, f);
  u += 0x7FFFu + ((u >> 16) & 1u);   // round-to-nearest-even
  return (unsigned short)(u >> 16);
}
__device__ __forceinline__ float sigmoid_f(float x) {
  return 1.f / (1.f + __expf(-x));
}
// NaN-safe fast tanh: 1 - 2/(e^{2x}+1)
__device__ __forceinline__ float tanh_f(float x) {
  float e = __expf(2.f * x);
  return 1.f - 2.f / (e + 1.f);
}

// ---------- cast+relayout primitive: one wave converts a 16row x 32col f32
// region to slot-major bf16 (region image: elem = s4*128 + r16*8 + e).
// Coalesced global reads, transpose via +1-padded LDS, contiguous 16B writes.
__device__ __forceinline__ void relayout_region(
    const float* __restrict__ srcRowBase, size_t rowStride,
    unsigned short* __restrict__ dst, float* __restrict__ lp, int lane) {
  {
    int r = lane >> 2, c = (lane & 3) << 3;
    const float* s = srcRowBase + (size_t)r * rowStride + c;
    f32x4 a = *(const f32x4*)(s);
    f32x4 b = *(const f32x4*)(s + 4);
#pragma unroll
    for (int j = 0; j < 4; ++j) { lp[r * 33 + c + j] = a[j]; lp[r * 33 + c + 4 + j] = b[j]; }
  }
  int s4 = lane >> 4, r16 = lane & 15;
  us8 o;
#pragma unroll
  for (int j = 0; j < 8; ++j) o[j] = f2bf(lp[r16 * 33 + s4 * 8 + j]);
  *(us8*)(dst + lane * 8) = o;
}

// ---------- ONE merged prep kernel: all relayouts in a single launch ----------
__global__ __launch_bounds__(256) void prep_all(
    const float* __restrict__ inp, const float* __restrict__ hidden,
    const float* __restrict__ w_ih, const float* __restrict__ w_hh,
    const float* __restrict__ w_out,
    unsigned short* __restrict__ inp_r, unsigned short* __restrict__ h_r,
    unsigned short* __restrict__ wih_r, unsigned short* __restrict__ whh_r,
    unsigned short* __restrict__ wout_r)
{
  __shared__ float lp[4][16 * 33];
  const int wIn = threadIdx.x >> 6, lane = threadIdx.x & 63;
  const int gw  = blockIdx.x * 4 + wIn;

  const float* src; unsigned short* dst; int K, local, isA;
  if      (gw < 2048) { src = inp;    dst = inp_r;  K = 512;  isA = 1; local = gw; }
  else if (gw < 6144) { src = hidden; dst = h_r;    K = 1024; isA = 1; local = gw - 2048; }
  else if (gw < 6912) { src = w_ih;   dst = wih_r;  K = 512;  isA = 0; local = gw - 6144; }
  else if (gw < 8448) { src = w_hh;   dst = whh_r;  K = 1024; isA = 0; local = gw - 6912; }
  else                { src = w_out;  dst = wout_r; K = 1024; isA = 1; local = gw - 8448; }
  const int nkt = K >> 5;

  if (isA) {
    int p = local / nkt, kt = local - p * nkt;
    const float* base = src + (size_t)p * 128 * K + kt * 32;
    unsigned short* d = dst + (size_t)local * 4096;
#pragma unroll
    for (int g = 0; g < 8; ++g)
      relayout_region(base + (size_t)g * 16 * K, K, d + g * 512, lp[wIn], lane);
  } else {
    int qg = local / nkt, kt = local - qg * nkt;
    int q = qg / 3, g = qg - q * 3;
    const float* base = src + ((size_t)g * 1024 + q * 64) * K + kt * 32;
    unsigned short* d = dst + (size_t)local * 2048;
#pragma unroll
    for (int rg = 0; rg < 4; ++rg)
      relayout_region(base + (size_t)rg * 16 * K, K, d + rg * 512, lp[wIn], lane);
  }
}

#define GLOAD(gp, lp) __builtin_amdgcn_global_load_lds( \
    (const __attribute__((address_space(1))) unsigned int*)(gp), \
    (__attribute__((address_space(3))) unsigned int*)(lp), 16, 0, 0)

// ---------- Fused GRU cell: r12 structure + concurrency-preserving XCD
// swizzle. bx = ((f&7)<<1)|((f>>3)&1), by = f>>4: blocks 16j..16j+15 still
// cover all 16 bx at by=j (identical concurrent working set to default),
// but XCD k (= f%8, round-robin) only ever touches bx in {2k,2k+1} -> its
// 1.2 MB W set stays L2-resident, removing W re-reads from L3. ----------
__global__ __launch_bounds__(256, 2) void fused_gru(
    const unsigned short* __restrict__ inp_r,
    const unsigned short* __restrict__ h_r,
    const unsigned short* __restrict__ wih_r,
    const unsigned short* __restrict__ whh_r,
    const float* __restrict__ b_ih,
    const float* __restrict__ b_hh,
    const float* __restrict__ hidden,      // [B,1024] f32
    float* __restrict__ hnew_f32,
    unsigned short* __restrict__ hnew_img)
{
  __shared__ unsigned short ls[4][10240];   // 4 x 20KB rotation

  const int tid  = threadIdx.x;
  const int lane = tid & 63;
  const int wave = tid >> 6;
  const int wr = wave >> 1, wc = wave & 1;

  const int f  = blockIdx.y * 16 + blockIdx.x;     // launch-order id
  const int bx = ((f & 7) << 1) | ((f >> 3) & 1);  // W-panel column 0..15
  const int by = f >> 4;                           // A row-panel 0..127

  f32x4 accR[4][2], accZ[4][2], accNi[4][2], accNh[4][2];
#pragma unroll
  for (int m = 0; m < 4; ++m)
#pragma unroll
    for (int n = 0; n < 2; ++n) {
      accR[m][n]  = f32x4{0.f, 0.f, 0.f, 0.f};
      accZ[m][n]  = f32x4{0.f, 0.f, 0.f, 0.f};
      accNi[m][n] = f32x4{0.f, 0.f, 0.f, 0.f};
      accNh[m][n] = f32x4{0.f, 0.f, 0.f, 0.f};
    }

  const int t4   = lane >> 4;                // k-octet 0..3
  const int l15  = lane & 15;
  const int rofs = t4 * 128 + l15 * 8;       // within-region read offset (elems)

  // induction staging pointers (wave-uniform; advance per step)
  const unsigned short* aptr = inp_r + (size_t)by * (16 * 4096);
  const unsigned short* wptr = wih_r + (size_t)bx * (3 * 16 * 2048);
  int wgs = 16 * 2048;                       // gate stride (elems)

#define STAGE(BUF) do { \
    GLOAD(aptr + tid * 8,           &ls[BUF][tid * 8]); \
    GLOAD(aptr + 2048 + tid * 8,    &ls[BUF][2048 + tid * 8]); \
    GLOAD(wptr + tid * 8,           &ls[BUF][4096 + tid * 8]); \
    GLOAD(wptr + wgs + tid * 8,     &ls[BUF][6144 + tid * 8]); \
    GLOAD(wptr + 2 * wgs + tid * 8, &ls[BUF][8192 + tid * 8]); \
    aptr += 4096; wptr += 2048; \
  } while (0)

#define COMPUTE(BUF, ACCN) do { \
    const unsigned short* lb = &ls[BUF][0]; \
    bf16x8 af[4], bfr[3][2]; \
    _Pragma("unroll") for (int m = 0; m < 4; ++m) \
      af[m] = *(const bf16x8*)&lb[(wr * 4 + m) * 512 + rofs]; \
    _Pragma("unroll") for (int g = 0; g < 3; ++g) { \
      _Pragma("unroll") for (int n = 0; n < 2; ++n) \
        bfr[g][n] = *(const bf16x8*)&lb[4096 + g * 2048 + (wc * 2 + n) * 512 + rofs]; \
    } \
    __builtin_amdgcn_s_setprio(1); \
    _Pragma("unroll") for (int m = 0; m < 4; ++m) { \
      _Pragma("unroll") for (int n = 0; n < 2; ++n) { \
        accR[m][n] = __builtin_amdgcn_mfma_f32_16x16x32_bf16(af[m], bfr[0][n], accR[m][n], 0, 0, 0); \
        accZ[m][n] = __builtin_amdgcn_mfma_f32_16x16x32_bf16(af[m], bfr[1][n], accZ[m][n], 0, 0, 0); \
        ACCN[m][n] = __builtin_amdgcn_mfma_f32_16x16x32_bf16(af[m], bfr[2][n], ACCN[m][n], 0, 0, 0); \
      } \
    } \
    __builtin_amdgcn_s_setprio(0); \
  } while (0)

#define WAIT10 asm volatile("s_waitcnt vmcnt(10)" ::: "memory")
#define BARR   __builtin_amdgcn_s_barrier()
#define STEP(SB, CB, ACCN) do { STAGE(SB); WAIT10; BARR; COMPUTE(CB, ACCN); } while (0)

  // 48 kt32 tiles: 0..15 inp/wih -> accNi, 16..47 h/whh -> accNh
  STAGE(0); STAGE(1);                        // tiles 0,1
#pragma unroll 1
  for (int i = 0; i < 3; ++i) {              // t = 0..11, stage 2..13
    STEP(2, 0, accNi); STEP(3, 1, accNi); STEP(0, 2, accNi); STEP(1, 3, accNi);
  }
  STEP(2, 0, accNi);                         // t=12, stage 14
  STEP(3, 1, accNi);                         // t=13, stage 15
  aptr = h_r + (size_t)by * (32 * 4096);     // switch to h-phase
  wptr = whh_r + (size_t)bx * (3 * 32 * 2048);
  wgs = 32 * 2048;
  STEP(0, 2, accNi);                         // t=14, stage 16
  STEP(1, 3, accNi);                         // t=15, stage 17
#pragma unroll 1
  for (int i = 0; i < 7; ++i) {              // t = 16..43, stage 18..45
    STEP(2, 0, accNh); STEP(3, 1, accNh); STEP(0, 2, accNh); STEP(1, 3, accNh);
  }
  STEP(2, 0, accNh);                         // t=44, stage 46
  STEP(3, 1, accNh);                         // t=45, stage 47
  asm volatile("s_waitcnt vmcnt(5)" ::: "memory"); BARR;
  COMPUTE(2, accNh);                         // t=46
  asm volatile("s_waitcnt vmcnt(0)" ::: "memory"); BARR;
  COMPUTE(3, accNh);                         // t=47

#undef STAGE
#undef COMPUTE
#undef WAIT10
#undef BARR
#undef STEP

  // ---- epilogue: gate math + blend ----
  // C/D layout: col = lane&15, row = (lane>>4)*4 + r
  const int m0 = by * 128;
  const int n0 = bx * 64;
  const int colb = n0 + wc * 32 + l15;
  const int rowb = m0 + wr * 64 + (t4 << 2);
#pragma unroll
  for (int n = 0; n < 2; ++n) {
    int c = colb + n * 16;
    float br  = b_ih[c]        + b_hh[c];
    float bz  = b_ih[1024 + c] + b_hh[1024 + c];
    float bni = b_ih[2048 + c];
    float bnh = b_hh[2048 + c];
    const int kt = c >> 5;                 // image k-chunk
    const int s  = (c >> 3) & 3;           // k-octet slot
    const int e  = c & 7;
#pragma unroll
    for (int m = 0; m < 4; ++m) {
      int row = rowb + m * 16;
#pragma unroll
      for (int r = 0; r < 4; ++r) {
        float rg = sigmoid_f(accR[m][n][r] + br);
        float zg = sigmoid_f(accZ[m][n][r] + bz);
        float ng = tanh_f((accNi[m][n][r] + bni) + rg * (accNh[m][n][r] + bnh));
        int rw = row + r;
        float ho = hidden[(size_t)rw * 1024 + c];
        float hv = (1.f - zg) * ng + zg * ho;
        hnew_f32[(size_t)rw * 1024 + c] = hv;
        // slot-major GEMM A-image: tile (p*32+kt), region (row>>4)&7
        size_t img = ((size_t)((rw >> 7) * 32 + kt)) * 4096
                   + (((rw >> 4) & 7) * 512) + s * 128 + (rw & 15) * 8 + e;
        hnew_img[img] = f2bf(hv);
      }
    }
  }
}

// ---------- out GEMM: r12 structure (no swizzle). ----------
__global__ __launch_bounds__(256, 2) void gemm_out(
    const unsigned short* __restrict__ A_img,   // [128 p-tiles][32 kt][4096]
    const unsigned short* __restrict__ B_img,   // [4 p-tiles][32 kt][4096]
    float* __restrict__ Cout,
    const float* __restrict__ bias)
{
  __shared__ unsigned short ls[4][8192];   // 4 x 16KB rotation (A 4096 | B 4096)

  const int tid  = threadIdx.x;
  const int lane = tid & 63;
  const int wave = tid >> 6;
  const int wr = wave >> 1, wc = wave & 1;

  f32x4 acc[4][4];
#pragma unroll
  for (int i = 0; i < 4; ++i)
#pragma unroll
    for (int j = 0; j < 4; ++j) acc[i][j] = f32x4{0.f, 0.f, 0.f, 0.f};

  const int t4   = lane >> 4;
  const int l15  = lane & 15;
  const int rofs = t4 * 128 + l15 * 8;

  const unsigned short* aptr = A_img + (size_t)blockIdx.y * (32 * 4096);
  const unsigned short* bptr = B_img + (size_t)blockIdx.x * (32 * 4096);

#define STAGE(BUF) do { \
    GLOAD(aptr + tid * 8,        &ls[BUF][tid * 8]); \
    GLOAD(aptr + 2048 + tid * 8, &ls[BUF][2048 + tid * 8]); \
    GLOAD(bptr + tid * 8,        &ls[BUF][4096 + tid * 8]); \
    GLOAD(bptr + 2048 + tid * 8, &ls[BUF][6144 + tid * 8]); \
    aptr += 4096; bptr += 4096; \
  } while (0)

#define COMPUTE(BUF) do { \
    const unsigned short* lb = &ls[BUF][0]; \
    bf16x8 af[4], bfr[4]; \
    _Pragma("unroll") for (int m = 0; m < 4; ++m) \
      af[m] = *(const bf16x8*)&lb[(wr * 4 + m) * 512 + rofs]; \
    _Pragma("unroll") for (int n = 0; n < 4; ++n) \
      bfr[n] = *(const bf16x8*)&lb[4096 + (wc * 4 + n) * 512 + rofs]; \
    __builtin_amdgcn_s_setprio(1); \
    _Pragma("unroll") for (int m = 0; m < 4; ++m) { \
      _Pragma("unroll") for (int n = 0; n < 4; ++n) \
        acc[m][n] = __builtin_amdgcn_mfma_f32_16x16x32_bf16(af[m], bfr[n], acc[m][n], 0, 0, 0); \
    } \
    __builtin_amdgcn_s_setprio(0); \
  } while (0)

#define WAIT8 asm volatile("s_waitcnt vmcnt(8)" ::: "memory")
#define BARR  __builtin_amdgcn_s_barrier()
#define STEP(SB, CB) do { STAGE(SB); WAIT8; BARR; COMPUTE(CB); } while (0)

  STAGE(0); STAGE(1);
#pragma unroll 1
  for (int i = 0; i < 7; ++i) {              // t = 0..27, stage 2..29
    STEP(2, 0); STEP(3, 1); STEP(0, 2); STEP(1, 3);
  }
  STEP(2, 0);                                // t=28, stage 30
  STEP(3, 1);                                // t=29, stage 31
  asm volatile("s_waitcnt vmcnt(4)" ::: "memory"); BARR;
  COMPUTE(2);                                // t=30
  asm volatile("s_waitcnt vmcnt(0)" ::: "memory"); BARR;
  COMPUTE(3);                                // t=31

#undef STAGE
#undef COMPUTE
#undef WAIT8
#undef BARR
#undef STEP

  const int m0 = blockIdx.y * 128;
  const int n0 = blockIdx.x * 128;
  const int colb = n0 + wc * 64 + l15;
  const int rowb = m0 + wr * 64 + (t4 << 2);
#pragma unroll
  for (int n = 0; n < 4; ++n) {
    int col = colb + n * 16;
    float bv = bias[col];
#pragma unroll
    for (int m = 0; m < 4; ++m) {
      int row = rowb + m * 16;
#pragma unroll
      for (int r = 0; r < 4; ++r) {
        Cout[(size_t)(row + r) * 512 + col] = tanh_f(acc[m][n][r] + bv);
      }
    }
  }
}

// ---------- launch ----------
extern "C" void kernel_launch(void* const* d_in, const int* in_sizes, int n_in,
                              void* d_out, int out_size, void* d_ws, size_t ws_size,
                              hipStream_t stream) {
  const int B = 16384, H = 1024, O = 512;
  const float* inp    = (const float*)d_in[0];
  const float* hidden = (const float*)d_in[1];
  const float* w_ih   = (const float*)d_in[2];
  const float* w_hh   = (const float*)d_in[3];
  const float* b_ih   = (const float*)d_in[4];
  const float* b_hh   = (const float*)d_in[5];
  const float* w_out  = (const float*)d_in[6];
  const float* b_out  = (const float*)d_in[7];

  float* out      = (float*)d_out;                     // [B, O] f32
  float* hnew_out = out + (size_t)B * O;               // [1, B, H] f32

  char* ws = (char*)d_ws;
  size_t need = 0;
  auto carve = [&](size_t elems) {
    unsigned short* p = (unsigned short*)(ws + need);
    need += elems * 2;
    return p;
  };
  unsigned short* inp_r  = carve((size_t)B * O);       // 16 MB (image)
  unsigned short* h_r    = carve((size_t)B * H);       // 32 MB (image)
  unsigned short* wih_r  = carve((size_t)3 * H * O);   // 3 MB (image)
  unsigned short* whh_r  = carve((size_t)3 * H * H);   // 6 MB (image)
  unsigned short* wout_r = carve((size_t)O * H);       // 1 MB (image)
  unsigned short* hnew_i = carve((size_t)B * H);       // 32 MB (image)
  if (ws_size < need) return;

  // one merged prep launch: 8576 waves -> 2144 blocks
  prep_all<<<dim3(2144), dim3(256), 0, stream>>>(
      inp, hidden, w_ih, w_hh, w_out, inp_r, h_r, wih_r, whh_r, wout_r);

  // fused GRU cell -> h_new (f32 into d_out tail, bf16 image into ws)
  fused_gru<<<dim3(H / 64, B / 128), dim3(256), 0, stream>>>(
      inp_r, h_r, wih_r, whh_r, b_ih, b_hh, hidden, hnew_out, hnew_i);

  // out = tanh(h_new @ w_out^T + b_out)
  gemm_out<<<dim3(O / 128, B / 128), dim3(256), 0, stream>>>(
      hnew_i, wout_r, out, b_out);
}